// Round 1
// baseline (174.569 us; speedup 1.0000x reference)
//
#include <hip/hip_runtime.h>

#define NROWS 4096
#define NCOLS 4096
#define TAU 0.95f
#define MARGIN 1.0f

// Kernel A: compute rerank hinge loss over 4096 adjacent (pos,neg) pairs and
// initialize d_out[0] with it (d_out is poisoned to 0xAA before every launch).
__global__ __launch_bounds__(256) void rerank_init_kernel(
    const float* __restrict__ y, float* __restrict__ out) {
  const int t = threadIdx.x;
  const float4* y4 = (const float4*)y;  // 8192 floats = 2048 float4; each float4 = 2 pairs
  float acc = 0.f;
#pragma unroll
  for (int i = 0; i < 8; ++i) {
    float4 v = y4[t + 256 * i];  // coalesced
    acc += fmaxf(0.f, MARGIN - (v.x - v.y));
    acc += fmaxf(0.f, MARGIN - (v.z - v.w));
  }
#pragma unroll
  for (int off = 32; off > 0; off >>= 1) acc += __shfl_down(acc, off, 64);
  __shared__ float ws[4];
  const int lane = t & 63, wid = t >> 6;
  if (lane == 0) ws[wid] = acc;
  __syncthreads();
  if (t == 0) {
    out[0] = (ws[0] + ws[1] + ws[2] + ws[3]) * (1.0f / 4096.0f);
  }
}

// Kernel B: one block per row. Block scan of labels -> cumsum c and total T.
// F1 weight simplifies exactly: r = (c>0) ? 2c/(k+T) : 0.
// Accumulate norm = sum(exp(r/tau)) and logsum = sum(log(cut_y)), then
// atomicAdd( -logsum/(norm*B) ).
__global__ __launch_bounds__(256) void attncut_kernel(
    const float* __restrict__ cut_y, const int* __restrict__ cut_label,
    float* __restrict__ out) {
  const int row = blockIdx.x;
  const int t = threadIdx.x;
  const int lane = t & 63;
  const int wid = t >> 6;

  const int4* lab4 = (const int4*)(cut_label + (size_t)row * NCOLS);
  const float4* y4 = (const float4*)(cut_y + (size_t)row * NCOLS);

  // Each thread owns 16 contiguous elements [t*16, t*16+16).
  int4 L[4];
  float4 Y[4];
#pragma unroll
  for (int i = 0; i < 4; ++i) L[i] = lab4[t * 4 + i];
#pragma unroll
  for (int i = 0; i < 4; ++i) Y[i] = y4[t * 4 + i];

  int labs[16];
  float ys[16];
#pragma unroll
  for (int i = 0; i < 4; ++i) {
    labs[i * 4 + 0] = (&L[i].x)[0];
    labs[i * 4 + 1] = (&L[i].x)[1];
    labs[i * 4 + 2] = (&L[i].x)[2];
    labs[i * 4 + 3] = (&L[i].x)[3];
    ys[i * 4 + 0] = (&Y[i].x)[0];
    ys[i * 4 + 1] = (&Y[i].x)[1];
    ys[i * 4 + 2] = (&Y[i].x)[2];
    ys[i * 4 + 3] = (&Y[i].x)[3];
  }

  int lsum = 0;
#pragma unroll
  for (int j = 0; j < 16; ++j) lsum += labs[j];

  // Wave-inclusive scan of per-thread sums (64 lanes).
  int x = lsum;
#pragma unroll
  for (int off = 1; off < 64; off <<= 1) {
    int v = __shfl_up(x, off, 64);
    if (lane >= off) x += v;
  }
  __shared__ int wsum[4];
  if (lane == 63) wsum[wid] = x;
  __syncthreads();
  int prev = 0;
#pragma unroll
  for (int w = 0; w < 4; ++w)
    if (w < wid) prev += wsum[w];
  const int Ttot = wsum[0] + wsum[1] + wsum[2] + wsum[3];
  int c = prev + x - lsum;  // exclusive prefix for this thread's chunk

  const float Tf = (float)Ttot;
  const float kbase = (float)(t * 16);
  float norm_acc = 0.f, log_acc = 0.f;
#pragma unroll
  for (int j = 0; j < 16; ++j) {
    c += labs[j];
    const float k = kbase + (float)(j + 1);
    const float r = (c > 0) ? __fdividef(2.0f * (float)c, k + Tf) : 0.0f;
    norm_acc += __expf(r * (1.0f / TAU));
    log_acc += __logf(ys[j]);
  }

  // Block reduction of (norm_acc, log_acc).
#pragma unroll
  for (int off = 32; off > 0; off >>= 1) {
    norm_acc += __shfl_down(norm_acc, off, 64);
    log_acc += __shfl_down(log_acc, off, 64);
  }
  __shared__ float nred[4], lred[4];
  if (lane == 0) {
    nred[wid] = norm_acc;
    lred[wid] = log_acc;
  }
  __syncthreads();
  if (t == 0) {
    const float norm = nred[0] + nred[1] + nred[2] + nred[3];
    const float ls = lred[0] + lred[1] + lred[2] + lred[3];
    atomicAdd(out, -ls / (norm * (float)NROWS));
  }
}

extern "C" void kernel_launch(void* const* d_in, const int* in_sizes, int n_in,
                              void* d_out, int out_size, void* d_ws, size_t ws_size,
                              hipStream_t stream) {
  const float* rerank_y = (const float*)d_in[0];   // (8192, 1) f32
  const float* cut_y = (const float*)d_in[1];      // (4096, 4096, 1) f32
  // d_in[2] = rerank_label, unused by the reference loss
  const int* cut_label = (const int*)d_in[3];      // (4096, 4096) i32
  float* out = (float*)d_out;                      // scalar f32

  rerank_init_kernel<<<1, 256, 0, stream>>>(rerank_y, out);
  attncut_kernel<<<NROWS, 256, 0, stream>>>(cut_y, cut_label, out);
}

// Round 2
// 173.684 us; speedup vs baseline: 1.0051x; 1.0051x over previous
//
#include <hip/hip_runtime.h>

#define NROWS 4096
#define NCOLS 4096
#define TAU 0.95f
#define MARGIN 1.0f

// Kernel A: rerank hinge loss over 4096 adjacent (pos,neg) pairs; initializes
// d_out[0] (harness poisons d_out before every launch).
__global__ __launch_bounds__(256) void rerank_init_kernel(
    const float* __restrict__ y, float* __restrict__ out) {
  const int t = threadIdx.x;
  const float4* y4 = (const float4*)y;  // 8192 floats; each float4 = 2 pairs
  float acc = 0.f;
#pragma unroll
  for (int i = 0; i < 8; ++i) {
    float4 v = y4[t + 256 * i];
    acc += fmaxf(0.f, MARGIN - (v.x - v.y));
    acc += fmaxf(0.f, MARGIN - (v.z - v.w));
  }
#pragma unroll
  for (int off = 32; off > 0; off >>= 1) acc += __shfl_down(acc, off, 64);
  __shared__ float ws[4];
  const int lane = t & 63, wid = t >> 6;
  if (lane == 0) ws[wid] = acc;
  __syncthreads();
  if (t == 0) out[0] = (ws[0] + ws[1] + ws[2] + ws[3]) * (1.0f / 4096.0f);
}

// Kernel B: one block per row (4096 cols). Each thread owns 16 contiguous
// elements held in named int4/float4 registers (NO arrays, NO address-of
// component indexing -> SROA keeps everything in VGPRs; R1's (&v.x)[j] trick
// forced scratch, VGPR_Count=24, 65us latency-bound).
// F1 weight simplifies exactly: r = (c>0) ? 2c/(k+T) : 0.
__global__ __launch_bounds__(256) void attncut_kernel(
    const float* __restrict__ cut_y, const int* __restrict__ cut_label,
    float* __restrict__ out) {
  const int row = blockIdx.x;
  const int t = threadIdx.x;
  const int lane = t & 63;
  const int wid = t >> 6;

  const int4* lab4 = (const int4*)(cut_label + (size_t)row * NCOLS) + t * 4;
  const float4* yy4 = (const float4*)(cut_y + (size_t)row * NCOLS) + t * 4;

  const int4 L0 = lab4[0], L1 = lab4[1], L2 = lab4[2], L3 = lab4[3];
  const float4 Y0 = yy4[0], Y1 = yy4[1], Y2 = yy4[2], Y3 = yy4[3];

  const int lsum = L0.x + L0.y + L0.z + L0.w + L1.x + L1.y + L1.z + L1.w +
                   L2.x + L2.y + L2.z + L2.w + L3.x + L3.y + L3.z + L3.w;

  // Wave-inclusive scan of per-thread label sums (64 lanes).
  int x = lsum;
#pragma unroll
  for (int off = 1; off < 64; off <<= 1) {
    int v = __shfl_up(x, off, 64);
    if (lane >= off) x += v;
  }
  __shared__ int wsum[4];
  if (lane == 63) wsum[wid] = x;
  __syncthreads();
  int prev = 0;
#pragma unroll
  for (int w = 0; w < 4; ++w)
    if (w < wid) prev += wsum[w];
  const int Ttot = wsum[0] + wsum[1] + wsum[2] + wsum[3];
  int c = prev + x - lsum;  // exclusive prefix for this thread's 16-chunk

  const float Tf = (float)Ttot;
  const float kbase = (float)(t * 16);
  float norm_acc = 0.f, log_acc = 0.f;

#define STEP(LAB, YV, J)                                           \
  {                                                                \
    c += (LAB);                                                    \
    const float kk = kbase + (float)((J) + 1);                     \
    const float r =                                                \
        (c > 0) ? __fdividef(2.0f * (float)c, kk + Tf) : 0.0f;     \
    norm_acc += __expf(r * (1.0f / TAU));                          \
    log_acc += __logf(YV);                                         \
  }

  STEP(L0.x, Y0.x, 0)  STEP(L0.y, Y0.y, 1)  STEP(L0.z, Y0.z, 2)  STEP(L0.w, Y0.w, 3)
  STEP(L1.x, Y1.x, 4)  STEP(L1.y, Y1.y, 5)  STEP(L1.z, Y1.z, 6)  STEP(L1.w, Y1.w, 7)
  STEP(L2.x, Y2.x, 8)  STEP(L2.y, Y2.y, 9)  STEP(L2.z, Y2.z, 10) STEP(L2.w, Y2.w, 11)
  STEP(L3.x, Y3.x, 12) STEP(L3.y, Y3.y, 13) STEP(L3.z, Y3.z, 14) STEP(L3.w, Y3.w, 15)
#undef STEP

  // Block reduction of (norm_acc, log_acc).
#pragma unroll
  for (int off = 32; off > 0; off >>= 1) {
    norm_acc += __shfl_down(norm_acc, off, 64);
    log_acc += __shfl_down(log_acc, off, 64);
  }
  __shared__ float nred[4], lred[4];
  if (lane == 0) {
    nred[wid] = norm_acc;
    lred[wid] = log_acc;
  }
  __syncthreads();
  if (t == 0) {
    const float norm = nred[0] + nred[1] + nred[2] + nred[3];
    const float ls = lred[0] + lred[1] + lred[2] + lred[3];
    atomicAdd(out, -ls / (norm * (float)NROWS));
  }
}

extern "C" void kernel_launch(void* const* d_in, const int* in_sizes, int n_in,
                              void* d_out, int out_size, void* d_ws, size_t ws_size,
                              hipStream_t stream) {
  const float* rerank_y = (const float*)d_in[0];   // (8192, 1) f32
  const float* cut_y = (const float*)d_in[1];      // (4096, 4096, 1) f32
  // d_in[2] = rerank_label, unused by the reference loss
  const int* cut_label = (const int*)d_in[3];      // (4096, 4096) i32
  float* out = (float*)d_out;                      // scalar f32

  rerank_init_kernel<<<1, 256, 0, stream>>>(rerank_y, out);
  attncut_kernel<<<NROWS, 256, 0, stream>>>(cut_y, cut_label, out);
}

// Round 3
// 151.219 us; speedup vs baseline: 1.1544x; 1.1486x over previous
//
#include <hip/hip_runtime.h>

#define NROWS 4096
#define NCOLS 4096
#define TAU 0.95f
#define MARGIN 1.0f

// Kernel 1: one block per row (identical to R2 except the single-address
// atomicAdd is replaced with a per-row partial store into d_ws -- R1/R2
// evidence: 65us wall independent of warmth AND of per-thread code; suspect
// same-address atomic serialization, 4096 x ~40cy ~= 65us).
__global__ __launch_bounds__(256) void attncut_kernel(
    const float* __restrict__ cut_y, const int* __restrict__ cut_label,
    float* __restrict__ partials) {
  const int row = blockIdx.x;
  const int t = threadIdx.x;
  const int lane = t & 63;
  const int wid = t >> 6;

  const int4* lab4 = (const int4*)(cut_label + (size_t)row * NCOLS) + t * 4;
  const float4* yy4 = (const float4*)(cut_y + (size_t)row * NCOLS) + t * 4;

  const int4 L0 = lab4[0], L1 = lab4[1], L2 = lab4[2], L3 = lab4[3];
  const float4 Y0 = yy4[0], Y1 = yy4[1], Y2 = yy4[2], Y3 = yy4[3];

  const int lsum = L0.x + L0.y + L0.z + L0.w + L1.x + L1.y + L1.z + L1.w +
                   L2.x + L2.y + L2.z + L2.w + L3.x + L3.y + L3.z + L3.w;

  // Wave-inclusive scan of per-thread label sums (64 lanes).
  int x = lsum;
#pragma unroll
  for (int off = 1; off < 64; off <<= 1) {
    int v = __shfl_up(x, off, 64);
    if (lane >= off) x += v;
  }
  __shared__ int wsum[4];
  if (lane == 63) wsum[wid] = x;
  __syncthreads();
  int prev = 0;
#pragma unroll
  for (int w = 0; w < 4; ++w)
    if (w < wid) prev += wsum[w];
  const int Ttot = wsum[0] + wsum[1] + wsum[2] + wsum[3];
  int c = prev + x - lsum;  // exclusive prefix for this thread's 16-chunk

  const float Tf = (float)Ttot;
  const float kbase = (float)(t * 16);
  float norm_acc = 0.f, log_acc = 0.f;

#define STEP(LAB, YV, J)                                           \
  {                                                                \
    c += (LAB);                                                    \
    const float kk = kbase + (float)((J) + 1);                     \
    const float r =                                                \
        (c > 0) ? __fdividef(2.0f * (float)c, kk + Tf) : 0.0f;     \
    norm_acc += __expf(r * (1.0f / TAU));                          \
    log_acc += __logf(YV);                                         \
  }

  STEP(L0.x, Y0.x, 0)  STEP(L0.y, Y0.y, 1)  STEP(L0.z, Y0.z, 2)  STEP(L0.w, Y0.w, 3)
  STEP(L1.x, Y1.x, 4)  STEP(L1.y, Y1.y, 5)  STEP(L1.z, Y1.z, 6)  STEP(L1.w, Y1.w, 7)
  STEP(L2.x, Y2.x, 8)  STEP(L2.y, Y2.y, 9)  STEP(L2.z, Y2.z, 10) STEP(L2.w, Y2.w, 11)
  STEP(L3.x, Y3.x, 12) STEP(L3.y, Y3.y, 13) STEP(L3.z, Y3.z, 14) STEP(L3.w, Y3.w, 15)
#undef STEP

  // Block reduction of (norm_acc, log_acc).
#pragma unroll
  for (int off = 32; off > 0; off >>= 1) {
    norm_acc += __shfl_down(norm_acc, off, 64);
    log_acc += __shfl_down(log_acc, off, 64);
  }
  __shared__ float nred[4], lred[4];
  if (lane == 0) {
    nred[wid] = norm_acc;
    lred[wid] = log_acc;
  }
  __syncthreads();
  if (t == 0) {
    const float norm = nred[0] + nred[1] + nred[2] + nred[3];
    const float ls = lred[0] + lred[1] + lred[2] + lred[3];
    partials[row] = -ls / (norm * (float)NROWS);  // distinct address per block
  }
}

// Kernel 2 (single block): sum the 4096 per-row partials + rerank hinge loss.
__global__ __launch_bounds__(256) void finish_kernel(
    const float* __restrict__ partials, const float* __restrict__ rerank_y,
    float* __restrict__ out) {
  const int t = threadIdx.x;
  const int lane = t & 63, wid = t >> 6;

  float acc = 0.f;
  const float4* p4 = (const float4*)partials;  // 4096 floats = 1024 float4
#pragma unroll
  for (int i = 0; i < 4; ++i) {
    float4 v = p4[t + 256 * i];
    acc += (v.x + v.y) + (v.z + v.w);
  }

  float racc = 0.f;
  const float4* y4 = (const float4*)rerank_y;  // 8192 floats; float4 = 2 pairs
#pragma unroll
  for (int i = 0; i < 8; ++i) {
    float4 v = y4[t + 256 * i];
    racc += fmaxf(0.f, MARGIN - (v.x - v.y));
    racc += fmaxf(0.f, MARGIN - (v.z - v.w));
  }
  acc += racc * (1.0f / 4096.0f);

#pragma unroll
  for (int off = 32; off > 0; off >>= 1) acc += __shfl_down(acc, off, 64);
  __shared__ float ws[4];
  if (lane == 0) ws[wid] = acc;
  __syncthreads();
  if (t == 0) out[0] = (ws[0] + ws[1]) + (ws[2] + ws[3]);
}

extern "C" void kernel_launch(void* const* d_in, const int* in_sizes, int n_in,
                              void* d_out, int out_size, void* d_ws, size_t ws_size,
                              hipStream_t stream) {
  const float* rerank_y = (const float*)d_in[0];   // (8192, 1) f32
  const float* cut_y = (const float*)d_in[1];      // (4096, 4096, 1) f32
  // d_in[2] = rerank_label, unused by the reference loss
  const int* cut_label = (const int*)d_in[3];      // (4096, 4096) i32
  float* out = (float*)d_out;                      // scalar f32
  float* partials = (float*)d_ws;                  // 4096 f32 (16 KB scratch)

  attncut_kernel<<<NROWS, 256, 0, stream>>>(cut_y, cut_label, partials);
  finish_kernel<<<1, 256, 0, stream>>>(partials, rerank_y, out);
}